// Round 7
// baseline (1085.672 us; speedup 1.0000x reference)
//
#include <hip/hip_runtime.h>
#include <hip/hip_cooperative_groups.h>

namespace cg = cooperative_groups;

#define N_NODES 50000
#define N_EDGES 800000
#define IN_F 256
#define OUT_F 64
#define HEADS 4
#define HF 256  // HEADS*OUT_F
#define NEG_SLOPE 0.2f

typedef __bf16 bf16x8 __attribute__((ext_vector_type(8)));
typedef float f32x4 __attribute__((ext_vector_type(4)));

// ---- monotone float<->uint encoding for atomicMax on floats ----
__device__ __forceinline__ unsigned encf(float f) {
  unsigned u = __float_as_uint(f);
  return (u & 0x80000000u) ? ~u : (u | 0x80000000u);
}
__device__ __forceinline__ float decf(unsigned k) {
  unsigned u = (k & 0x80000000u) ? (k & 0x7FFFFFFFu) : ~k;
  return __uint_as_float(u);
}
// fp32 -> bf16 (round-to-nearest-even)
__device__ __forceinline__ unsigned short f2bf(float f) {
  unsigned u = __float_as_uint(f);
  u += 0x7FFFu + ((u >> 16) & 1u);
  return (unsigned short)(u >> 16);
}
__device__ __forceinline__ float bflo(unsigned u) { return __uint_as_float(u << 16); }
__device__ __forceinline__ float bfhi(unsigned u) { return __uint_as_float(u & 0xFFFF0000u); }

// ======================= FUSED COOPERATIVE KERNEL =========================
// Grid-size agnostic: every phase strides by gridDim.x. Launched with
// nb = min(1024, runtime cooperative capacity). Falls back to the
// multi-kernel path if the cooperative launch is rejected.
__global__ __launch_bounds__(256, 4) void k_all(
    const float* __restrict__ x, const int* __restrict__ src,
    const int* __restrict__ dst, const float* __restrict__ ew,
    const float* __restrict__ W, const float* __restrict__ a_src,
    const float* __restrict__ a_dst, unsigned short* __restrict__ xb,
    unsigned short* __restrict__ wb, unsigned short* __restrict__ hb,
    float* __restrict__ as, float* __restrict__ ad, int* __restrict__ deg,
    int* __restrict__ row_start, int* __restrict__ cursor,
    int2* __restrict__ rec, int* __restrict__ bsum,
    unsigned* __restrict__ gmax, float* __restrict__ out) {
  cg::grid_group gg = cg::this_grid();
  __shared__ float sal[4][4][68];
  __shared__ float redf[4];
  __shared__ int redi[4];

  const int t = threadIdx.x;
  const int nb = gridDim.x;
  const int nth = nb * 256;
  const int tid = blockIdx.x * 256 + t;
  const int wv = t >> 6, lane = t & 63;
  const int npb = (N_NODES + nb - 1) / nb;  // nodes per block (scan phases)

  // ===== phase 0: pack W, zero deg/gmax, pack x (f32->bf16) =====
  for (int i = tid; i < 65536; i += nth) {
    int j = i & 7, l = (i >> 3) & 63, kt = (i >> 9) & 7;
    int w = (i >> 12) & 3, hd = (i >> 14) & 3;
    int k = kt * 32 + (l >> 4) * 8 + j;
    int o = w * 16 + (l & 15);
    wb[i] = f2bf(W[((size_t)hd * IN_F + k) * OUT_F + o]);
  }
  for (int i = tid; i < N_NODES; i += nth) deg[i] = 0;
  if (tid == 0) *gmax = 0u;
  for (int i = tid; i < N_NODES * IN_F / 8; i += nth) {
    const float* px = x + (size_t)i * 8;
    float4 v0 = *(const float4*)px;
    float4 v1 = *(const float4*)(px + 4);
    uint4 o;
    o.x = (unsigned)f2bf(v0.x) | ((unsigned)f2bf(v0.y) << 16);
    o.y = (unsigned)f2bf(v0.z) | ((unsigned)f2bf(v0.w) << 16);
    o.z = (unsigned)f2bf(v1.x) | ((unsigned)f2bf(v1.y) << 16);
    o.w = (unsigned)f2bf(v1.z) | ((unsigned)f2bf(v1.w) << 16);
    *(uint4*)(xb + (size_t)i * 8) = o;
  }
  __threadfence();
  gg.sync();

  // ===== phase 1: MFMA gemm, grid-strided over 782 row-tiles =====
  for (int blk = blockIdx.x; blk < 782; blk += nb) {
    const int hd = wv, quad = lane >> 4, col = lane & 15;
    f32x4 acc[4][4];
#pragma unroll
    for (int ms = 0; ms < 4; ms++)
#pragma unroll
      for (int nt = 0; nt < 4; nt++) acc[ms][nt] = (f32x4){0.f, 0.f, 0.f, 0.f};

    const unsigned short* ab[4];
#pragma unroll
    for (int ms = 0; ms < 4; ms++) {
      int mt = blk * 4 + ms;
      if (mt > 3124) mt = 3124;  // tail: dup compute, stores guarded by m<N
      ab[ms] = xb + (size_t)(mt * 16 + col) * IN_F + quad * 8;
    }
    const unsigned short* wbase = wb + (size_t)hd * 16384 + lane * 8;

    for (int kt = 0; kt < 8; kt++) {
      union { uint4 u; bf16x8 v; } b[4], a[4];
#pragma unroll
      for (int nt = 0; nt < 4; nt++)
        b[nt].u = *(const uint4*)(wbase + (nt * 8 + kt) * 512);
#pragma unroll
      for (int ms = 0; ms < 4; ms++)
        a[ms].u = *(const uint4*)(ab[ms] + kt * 32);
#pragma unroll
      for (int ms = 0; ms < 4; ms++)
#pragma unroll
        for (int nt = 0; nt < 4; nt++)
          acc[ms][nt] = __builtin_amdgcn_mfma_f32_16x16x32_bf16(a[ms].v, b[nt].v, acc[ms][nt], 0, 0, 0);
    }

    // C/D layout: col = lane&15, row = quad*4 + r  [verified m89/m91]
    float avs[4], avd[4];
#pragma unroll
    for (int nt = 0; nt < 4; nt++) {
      avs[nt] = a_src[hd * OUT_F + nt * 16 + col];
      avd[nt] = a_dst[hd * OUT_F + nt * 16 + col];
    }
#pragma unroll
    for (int ms = 0; ms < 4; ms++) {
      int mbase = blk * 64 + ms * 16 + quad * 4;
#pragma unroll
      for (int r = 0; r < 4; r++) {
        int m = mbase + r;
        float ps = 0.f, pd = 0.f;
#pragma unroll
        for (int nt = 0; nt < 4; nt++) {
          float hv = acc[ms][nt][r];
          if (m < N_NODES)
            hb[(size_t)m * HF + hd * OUT_F + nt * 16 + col] = f2bf(hv);
          ps += hv * avs[nt];
          pd += hv * avd[nt];
        }
#pragma unroll
        for (int off = 8; off > 0; off >>= 1) {
          ps += __shfl_down(ps, off, 16);
          pd += __shfl_down(pd, off, 16);
        }
        if (col == 0 && m < N_NODES) {
          as[m * 4 + hd] = ps;   // [node][head] interleaved
          ad[m * 4 + hd] = pd;
        }
      }
    }
  }
  __threadfence();
  gg.sync();

  // ===== phase 2: global edge max + dst-degree histogram =====
  {
    float mx = -3.4e38f;
    for (int e = tid; e < N_EDGES; e += nth) {
      int s = src[e], d = dst[e];
      float w = ew[e];
      atomicAdd(deg + d, 1);
      float4 a = *(const float4*)(as + (size_t)s * 4);
      float4 b = *(const float4*)(ad + (size_t)d * 4);
      float v0 = a.x + b.x, v1 = a.y + b.y, v2 = a.z + b.z, v3 = a.w + b.w;
      v0 = v0 >= 0.f ? v0 : NEG_SLOPE * v0;
      v1 = v1 >= 0.f ? v1 : NEG_SLOPE * v1;
      v2 = v2 >= 0.f ? v2 : NEG_SLOPE * v2;
      v3 = v3 >= 0.f ? v3 : NEG_SLOPE * v3;
      mx = fmaxf(mx, fmaxf(fmaxf(v0 * w, v1 * w), fmaxf(v2 * w, v3 * w)));
    }
#pragma unroll
    for (int off = 32; off > 0; off >>= 1) mx = fmaxf(mx, __shfl_down(mx, off));
    if (lane == 0) redf[wv] = mx;
    __syncthreads();
    if (t == 0) {
      float mm = fmaxf(fmaxf(redf[0], redf[1]), fmaxf(redf[2], redf[3]));
      atomicMax(gmax, encf(mm));
    }
  }
  __threadfence();
  gg.sync();

  // ===== phase 3: per-block scan. Block b owns nodes [b*npb, b*npb+npb).
  // Writes exclusive-within-block into row_start; block total into bsum[b].
  if (wv == 0) {
    int base0 = blockIdx.x * npb;
    int carry = 0;
    for (int off = 0; off < npb; off += 64) {
      int i = off + lane;
      int node = base0 + i;
      int orig = (i < npb && node < N_NODES) ? deg[node] : 0;
      int v = orig;
#pragma unroll
      for (int s = 1; s < 64; s <<= 1) {
        int u = __shfl_up(v, s);
        if (lane >= s) v += u;
      }
      if (i < npb && node < N_NODES) row_start[node] = carry + v - orig;
      carry += __shfl(v, 63);
    }
    if (lane == 0) bsum[blockIdx.x] = carry;
  }
  __threadfence();
  gg.sync();

  // ===== phase 4: block 0 scans bsum[nb] exclusive (chunked, any nb) =====
  if (blockIdx.x == 0) {
    int carry = 0;
    for (int base = 0; base < nb; base += 256) {
      int idx = base + t;
      int orig = (idx < nb) ? bsum[idx] : 0;
      int v = orig;
#pragma unroll
      for (int s = 1; s < 64; s <<= 1) {
        int u = __shfl_up(v, s);
        if (lane >= s) v += u;
      }
      if (lane == 63) redi[wv] = v;
      __syncthreads();
      int wbase = 0;
      for (int w2 = 0; w2 < wv; w2++) wbase += redi[w2];
      int btot = redi[0] + redi[1] + redi[2] + redi[3];
      if (idx < nb) bsum[idx] = carry + wbase + v - orig;
      carry += btot;
      __syncthreads();
    }
  }
  __threadfence();
  gg.sync();

  // ===== phase 5: row_start += block offset; init cursor =====
  {
    int base0 = blockIdx.x * npb;
    int bo = bsum[blockIdx.x];
    for (int i = t; i < npb; i += 256) {
      int node = base0 + i;
      if (node < N_NODES) {
        int rs = row_start[node] + bo;
        row_start[node] = rs;
        cursor[node] = rs;
      }
    }
  }
  __threadfence();
  gg.sync();

  // ===== phase 6: counting-sort scatter (src, ew) =====
  for (int e = tid; e < N_EDGES; e += nth) {
    int s = src[e], d = dst[e];
    float w = ew[e];
    int pos = atomicAdd(cursor + d, 1);
    rec[pos] = make_int2(s, __float_as_int(w));
  }
  __threadfence();
  gg.sync();

  // ===== phase 7: aggregation, one node per wave, grid-strided =====
  {
    const float gm = decf(*gmax);
    const int half = lane >> 5, li = lane & 31;
    const int hd8 = li >> 3;
    for (int d = blockIdx.x * 4 + wv; d < N_NODES; d += nb * 4) {
      const int rs = row_start[d];
      const int dg = deg[d];
      const float4 adv = *(const float4*)(ad + (size_t)d * 4);
      float ax = 0.f, ay = 0.f, az = 0.f, aw = 0.f;
      float bx = 0.f, by = 0.f, bz = 0.f, bw = 0.f;
      float den = 0.f;

      for (int j0 = 0; j0 < dg; j0 += 64) {
        const int nj = min(64, dg - j0);
        int se = 0;
        float we = 0.f;
        if (lane < nj) {
          int2 r = rec[rs + j0 + lane];
          se = r.x;
          we = __int_as_float(r.y);
        }
        {
          float4 a4 = *(const float4*)(as + (size_t)se * 4);
          float v0 = a4.x + adv.x;
          float v1 = a4.y + adv.y;
          float v2 = a4.z + adv.z;
          float v3 = a4.w + adv.w;
          v0 = v0 >= 0.f ? v0 : NEG_SLOPE * v0;
          v1 = v1 >= 0.f ? v1 : NEG_SLOPE * v1;
          v2 = v2 >= 0.f ? v2 : NEG_SLOPE * v2;
          v3 = v3 >= 0.f ? v3 : NEG_SLOPE * v3;
          bool ok = lane < nj;
          sal[wv][0][lane] = ok ? __expf(v0 * we - gm) : 0.f;
          sal[wv][1][lane] = ok ? __expf(v1 * we - gm) : 0.f;
          sal[wv][2][lane] = ok ? __expf(v2 * we - gm) : 0.f;
          sal[wv][3][lane] = ok ? __expf(v3 * we - gm) : 0.f;
        }
        asm volatile("s_waitcnt lgkmcnt(0)" ::: "memory");
        const float* salh = sal[wv][hd8];

        int j = 0;
        for (; j + 7 < nj; j += 8) {
          int sj0 = __shfl(se, j + half);
          int sj1 = __shfl(se, j + 2 + half);
          int sj2 = __shfl(se, j + 4 + half);
          int sj3 = __shfl(se, j + 6 + half);
          uint4 q0 = *(const uint4*)(hb + (size_t)sj0 * HF + li * 8);
          uint4 q1 = *(const uint4*)(hb + (size_t)sj1 * HF + li * 8);
          uint4 q2 = *(const uint4*)(hb + (size_t)sj2 * HF + li * 8);
          uint4 q3 = *(const uint4*)(hb + (size_t)sj3 * HF + li * 8);
          float a0 = salh[j + half];
          float a1 = salh[j + 2 + half];
          float a2 = salh[j + 4 + half];
          float a3 = salh[j + 6 + half];
          den += (a0 + a1) + (a2 + a3);
          ax += a0 * bflo(q0.x) + a1 * bflo(q1.x) + a2 * bflo(q2.x) + a3 * bflo(q3.x);
          ay += a0 * bfhi(q0.x) + a1 * bfhi(q1.x) + a2 * bfhi(q2.x) + a3 * bfhi(q3.x);
          az += a0 * bflo(q0.y) + a1 * bflo(q1.y) + a2 * bflo(q2.y) + a3 * bflo(q3.y);
          aw += a0 * bfhi(q0.y) + a1 * bfhi(q1.y) + a2 * bfhi(q2.y) + a3 * bfhi(q3.y);
          bx += a0 * bflo(q0.z) + a1 * bflo(q1.z) + a2 * bflo(q2.z) + a3 * bflo(q3.z);
          by += a0 * bfhi(q0.z) + a1 * bfhi(q1.z) + a2 * bfhi(q2.z) + a3 * bfhi(q3.z);
          bz += a0 * bflo(q0.w) + a1 * bflo(q1.w) + a2 * bflo(q2.w) + a3 * bflo(q3.w);
          bw += a0 * bfhi(q0.w) + a1 * bfhi(q1.w) + a2 * bfhi(q2.w) + a3 * bfhi(q3.w);
        }
        for (; j < nj; j += 2) {
          int sj0 = __shfl(se, min(j + half, nj - 1));
          float a0 = (j + half < nj) ? salh[j + half] : 0.f;
          uint4 q0 = *(const uint4*)(hb + (size_t)sj0 * HF + li * 8);
          den += a0;
          ax += a0 * bflo(q0.x);
          ay += a0 * bfhi(q0.x);
          az += a0 * bflo(q0.y);
          aw += a0 * bfhi(q0.y);
          bx += a0 * bflo(q0.z);
          by += a0 * bfhi(q0.z);
          bz += a0 * bflo(q0.w);
          bw += a0 * bfhi(q0.w);
        }
      }

      ax += __shfl_xor(ax, 32); ay += __shfl_xor(ay, 32);
      az += __shfl_xor(az, 32); aw += __shfl_xor(aw, 32);
      bx += __shfl_xor(bx, 32); by += __shfl_xor(by, 32);
      bz += __shfl_xor(bz, 32); bw += __shfl_xor(bw, 32);
      den += __shfl_xor(den, 32);
      float inv = 1.f / (den + 1e-10f);
      float4 r;
      if (half == 0) r = make_float4(ax * inv, ay * inv, az * inv, aw * inv);
      else           r = make_float4(bx * inv, by * inv, bz * inv, bw * inv);
      *(float4*)(out + (size_t)d * HF + li * 8 + half * 4) = r;
    }
  }
}

// ======================= FALLBACK MULTI-KERNEL PATH (verified R5) =========
__global__ __launch_bounds__(256) void k_pack_w(const float* __restrict__ W,
                                                unsigned short* __restrict__ wb,
                                                int* __restrict__ deg,
                                                unsigned* __restrict__ gmax) {
  int idx = blockIdx.x * 256 + threadIdx.x;
  if (idx < N_NODES) deg[idx] = 0;
  if (idx == 0) *gmax = 0u;
  int j = idx & 7, l = (idx >> 3) & 63, kt = (idx >> 9) & 7;
  int w = (idx >> 12) & 3, hd = (idx >> 14) & 3;
  int k = kt * 32 + (l >> 4) * 8 + j;
  int o = w * 16 + (l & 15);
  wb[idx] = f2bf(W[((size_t)hd * IN_F + k) * OUT_F + o]);
}

__global__ __launch_bounds__(256) void k_pack_x(const float* __restrict__ x,
                                                unsigned short* __restrict__ xb) {
  int tid = blockIdx.x * 256 + threadIdx.x;
  const float* px = x + (size_t)tid * 8;
  float4 v0 = *(const float4*)px;
  float4 v1 = *(const float4*)(px + 4);
  uint4 o;
  o.x = (unsigned)f2bf(v0.x) | ((unsigned)f2bf(v0.y) << 16);
  o.y = (unsigned)f2bf(v0.z) | ((unsigned)f2bf(v0.w) << 16);
  o.z = (unsigned)f2bf(v1.x) | ((unsigned)f2bf(v1.y) << 16);
  o.w = (unsigned)f2bf(v1.z) | ((unsigned)f2bf(v1.w) << 16);
  *(uint4*)(xb + (size_t)tid * 8) = o;
}

__global__ __launch_bounds__(256) void k_gemm(const unsigned short* __restrict__ xb,
                                              const unsigned short* __restrict__ wb,
                                              const float* __restrict__ a_src,
                                              const float* __restrict__ a_dst,
                                              unsigned short* __restrict__ hb,
                                              float* __restrict__ as_out,
                                              float* __restrict__ ad_out) {
  const int t = threadIdx.x;
  const int hd = t >> 6, l = t & 63;
  const int quad = l >> 4, col = l & 15;
  const int blk = blockIdx.x;
  f32x4 acc[4][4];
#pragma unroll
  for (int ms = 0; ms < 4; ms++)
#pragma unroll
    for (int nt = 0; nt < 4; nt++) acc[ms][nt] = (f32x4){0.f, 0.f, 0.f, 0.f};
  const unsigned short* ab[4];
#pragma unroll
  for (int ms = 0; ms < 4; ms++) {
    int mt = blk * 4 + ms;
    if (mt > 3124) mt = 3124;
    ab[ms] = xb + (size_t)(mt * 16 + col) * IN_F + quad * 8;
  }
  const unsigned short* wbase = wb + (size_t)hd * 16384 + l * 8;
  for (int kt = 0; kt < 8; kt++) {
    union { uint4 u; bf16x8 v; } b[4], a[4];
#pragma unroll
    for (int nt = 0; nt < 4; nt++)
      b[nt].u = *(const uint4*)(wbase + (nt * 8 + kt) * 512);
#pragma unroll
    for (int ms = 0; ms < 4; ms++)
      a[ms].u = *(const uint4*)(ab[ms] + kt * 32);
#pragma unroll
    for (int ms = 0; ms < 4; ms++)
#pragma unroll
      for (int nt = 0; nt < 4; nt++)
        acc[ms][nt] = __builtin_amdgcn_mfma_f32_16x16x32_bf16(a[ms].v, b[nt].v, acc[ms][nt], 0, 0, 0);
  }
  float avs[4], avd[4];
#pragma unroll
  for (int nt = 0; nt < 4; nt++) {
    avs[nt] = a_src[hd * OUT_F + nt * 16 + col];
    avd[nt] = a_dst[hd * OUT_F + nt * 16 + col];
  }
#pragma unroll
  for (int ms = 0; ms < 4; ms++) {
    int mbase = blk * 64 + ms * 16 + quad * 4;
#pragma unroll
    for (int r = 0; r < 4; r++) {
      int m = mbase + r;
      float ps = 0.f, pd = 0.f;
#pragma unroll
      for (int nt = 0; nt < 4; nt++) {
        float hv = acc[ms][nt][r];
        if (m < N_NODES)
          hb[(size_t)m * HF + hd * OUT_F + nt * 16 + col] = f2bf(hv);
        ps += hv * avs[nt];
        pd += hv * avd[nt];
      }
#pragma unroll
      for (int off = 8; off > 0; off >>= 1) {
        ps += __shfl_down(ps, off, 16);
        pd += __shfl_down(pd, off, 16);
      }
      if (col == 0 && m < N_NODES) {
        as_out[m * 4 + hd] = ps;
        ad_out[m * 4 + hd] = pd;
      }
    }
  }
}

__global__ __launch_bounds__(256) void k_edge_max(const int* __restrict__ src,
                                                  const int* __restrict__ dst,
                                                  const float* __restrict__ ew,
                                                  const float* __restrict__ as,
                                                  const float* __restrict__ ad,
                                                  unsigned* __restrict__ gmax,
                                                  int* __restrict__ deg) {
  int e = blockIdx.x * 256 + threadIdx.x;
  int s = src[e], d = dst[e];
  float w = ew[e];
  atomicAdd(deg + d, 1);
  float4 a = *(const float4*)(as + (size_t)s * 4);
  float4 b = *(const float4*)(ad + (size_t)d * 4);
  float v0 = a.x + b.x, v1 = a.y + b.y, v2 = a.z + b.z, v3 = a.w + b.w;
  v0 = v0 >= 0.f ? v0 : NEG_SLOPE * v0;
  v1 = v1 >= 0.f ? v1 : NEG_SLOPE * v1;
  v2 = v2 >= 0.f ? v2 : NEG_SLOPE * v2;
  v3 = v3 >= 0.f ? v3 : NEG_SLOPE * v3;
  float m = fmaxf(fmaxf(v0 * w, v1 * w), fmaxf(v2 * w, v3 * w));
#pragma unroll
  for (int off = 32; off > 0; off >>= 1) m = fmaxf(m, __shfl_down(m, off));
  __shared__ float red[4];
  int wave = threadIdx.x >> 6, lane = threadIdx.x & 63;
  if (lane == 0) red[wave] = m;
  __syncthreads();
  if (threadIdx.x == 0) {
    float mm = fmaxf(fmaxf(red[0], red[1]), fmaxf(red[2], red[3]));
    atomicMax(gmax, encf(mm));
  }
}

__global__ __launch_bounds__(256) void k_scan1(const int* __restrict__ deg,
                                               int* __restrict__ excl,
                                               int* __restrict__ bsum) {
  int i = blockIdx.x * 256 + threadIdx.x;
  int orig = (i < N_NODES) ? deg[i] : 0;
  int v = orig;
  int lane = threadIdx.x & 63, wave = threadIdx.x >> 6;
#pragma unroll
  for (int off = 1; off < 64; off <<= 1) {
    int u = __shfl_up(v, off);
    if (lane >= off) v += u;
  }
  __shared__ int wsum[4];
  if (lane == 63) wsum[wave] = v;
  __syncthreads();
  int base = 0;
  for (int w = 0; w < wave; w++) base += wsum[w];
  int incl = v + base;
  if (i < N_NODES) excl[i] = incl - orig;
  if (threadIdx.x == 255) bsum[blockIdx.x] = incl;
}

__global__ __launch_bounds__(256) void k_scan2(int* __restrict__ bsum, int nbk) {
  int t = threadIdx.x;
  int orig = (t < nbk) ? bsum[t] : 0;
  int v = orig;
  int lane = t & 63, wave = t >> 6;
#pragma unroll
  for (int off = 1; off < 64; off <<= 1) {
    int u = __shfl_up(v, off);
    if (lane >= off) v += u;
  }
  __shared__ int wsum[4];
  if (lane == 63) wsum[wave] = v;
  __syncthreads();
  int base = 0;
  for (int w = 0; w < wave; w++) base += wsum[w];
  if (t < nbk) bsum[t] = v + base - orig;
}

__global__ __launch_bounds__(256) void k_scan3(const int* __restrict__ excl,
                                               const int* __restrict__ bsum,
                                               int* __restrict__ row_start,
                                               int* __restrict__ cursor) {
  int i = blockIdx.x * 256 + threadIdx.x;
  if (i < N_NODES) {
    int rs = excl[i] + bsum[blockIdx.x];
    row_start[i] = rs;
    cursor[i] = rs;
  }
}

__global__ __launch_bounds__(256) void k_scatter(const int* __restrict__ src,
                                                 const int* __restrict__ dst,
                                                 const float* __restrict__ ew,
                                                 int* __restrict__ cursor,
                                                 int2* __restrict__ rec) {
  int e = blockIdx.x * 256 + threadIdx.x;
  int s = src[e], d = dst[e];
  float w = ew[e];
  int pos = atomicAdd(cursor + d, 1);
  rec[pos] = make_int2(s, __float_as_int(w));
}

__global__ __launch_bounds__(256) void k_agg(const int* __restrict__ row_start,
                                             const int* __restrict__ deg,
                                             const int2* __restrict__ rec,
                                             const float* __restrict__ as,
                                             const float* __restrict__ ad,
                                             const unsigned* __restrict__ gmax,
                                             const unsigned short* __restrict__ hb,
                                             float* __restrict__ out) {
  __shared__ float sal[4][4][68];
  const int t = threadIdx.x;
  const int wv = t >> 6, lane = t & 63;
  const int half = lane >> 5, li = lane & 31;
  const int hd8 = li >> 3;
  const int d = blockIdx.x * 4 + wv;
  const int rs = row_start[d];
  const int dg = deg[d];
  const float gm = decf(*gmax);
  const float4 adv = *(const float4*)(ad + (size_t)d * 4);
  float ax = 0.f, ay = 0.f, az = 0.f, aw = 0.f;
  float bx = 0.f, by = 0.f, bz = 0.f, bw = 0.f;
  float den = 0.f;

  for (int j0 = 0; j0 < dg; j0 += 64) {
    const int nj = min(64, dg - j0);
    int se = 0;
    float we = 0.f;
    if (lane < nj) {
      int2 r = rec[rs + j0 + lane];
      se = r.x;
      we = __int_as_float(r.y);
    }
    {
      float4 a4 = *(const float4*)(as + (size_t)se * 4);
      float v0 = a4.x + adv.x;
      float v1 = a4.y + adv.y;
      float v2 = a4.z + adv.z;
      float v3 = a4.w + adv.w;
      v0 = v0 >= 0.f ? v0 : NEG_SLOPE * v0;
      v1 = v1 >= 0.f ? v1 : NEG_SLOPE * v1;
      v2 = v2 >= 0.f ? v2 : NEG_SLOPE * v2;
      v3 = v3 >= 0.f ? v3 : NEG_SLOPE * v3;
      bool ok = lane < nj;
      sal[wv][0][lane] = ok ? __expf(v0 * we - gm) : 0.f;
      sal[wv][1][lane] = ok ? __expf(v1 * we - gm) : 0.f;
      sal[wv][2][lane] = ok ? __expf(v2 * we - gm) : 0.f;
      sal[wv][3][lane] = ok ? __expf(v3 * we - gm) : 0.f;
    }
    asm volatile("s_waitcnt lgkmcnt(0)" ::: "memory");
    const float* salh = sal[wv][hd8];

    int j = 0;
    for (; j + 7 < nj; j += 8) {
      int sj0 = __shfl(se, j + half);
      int sj1 = __shfl(se, j + 2 + half);
      int sj2 = __shfl(se, j + 4 + half);
      int sj3 = __shfl(se, j + 6 + half);
      uint4 q0 = *(const uint4*)(hb + (size_t)sj0 * HF + li * 8);
      uint4 q1 = *(const uint4*)(hb + (size_t)sj1 * HF + li * 8);
      uint4 q2 = *(const uint4*)(hb + (size_t)sj2 * HF + li * 8);
      uint4 q3 = *(const uint4*)(hb + (size_t)sj3 * HF + li * 8);
      float a0 = salh[j + half];
      float a1 = salh[j + 2 + half];
      float a2 = salh[j + 4 + half];
      float a3 = salh[j + 6 + half];
      den += (a0 + a1) + (a2 + a3);
      ax += a0 * bflo(q0.x) + a1 * bflo(q1.x) + a2 * bflo(q2.x) + a3 * bflo(q3.x);
      ay += a0 * bfhi(q0.x) + a1 * bfhi(q1.x) + a2 * bfhi(q2.x) + a3 * bfhi(q3.x);
      az += a0 * bflo(q0.y) + a1 * bflo(q1.y) + a2 * bflo(q2.y) + a3 * bflo(q3.y);
      aw += a0 * bfhi(q0.y) + a1 * bfhi(q1.y) + a2 * bfhi(q2.y) + a3 * bfhi(q3.y);
      bx += a0 * bflo(q0.z) + a1 * bflo(q1.z) + a2 * bflo(q2.z) + a3 * bflo(q3.z);
      by += a0 * bfhi(q0.z) + a1 * bfhi(q1.z) + a2 * bfhi(q2.z) + a3 * bfhi(q3.z);
      bz += a0 * bflo(q0.w) + a1 * bflo(q1.w) + a2 * bflo(q2.w) + a3 * bflo(q3.w);
      bw += a0 * bfhi(q0.w) + a1 * bfhi(q1.w) + a2 * bfhi(q2.w) + a3 * bfhi(q3.w);
    }
    for (; j < nj; j += 2) {
      int sj0 = __shfl(se, min(j + half, nj - 1));
      float a0 = (j + half < nj) ? salh[j + half] : 0.f;
      uint4 q0 = *(const uint4*)(hb + (size_t)sj0 * HF + li * 8);
      den += a0;
      ax += a0 * bflo(q0.x);
      ay += a0 * bfhi(q0.x);
      az += a0 * bflo(q0.y);
      aw += a0 * bfhi(q0.y);
      bx += a0 * bflo(q0.z);
      by += a0 * bfhi(q0.z);
      bz += a0 * bflo(q0.w);
      bw += a0 * bfhi(q0.w);
    }
  }

  ax += __shfl_xor(ax, 32); ay += __shfl_xor(ay, 32);
  az += __shfl_xor(az, 32); aw += __shfl_xor(aw, 32);
  bx += __shfl_xor(bx, 32); by += __shfl_xor(by, 32);
  bz += __shfl_xor(bz, 32); bw += __shfl_xor(bw, 32);
  den += __shfl_xor(den, 32);
  float inv = 1.f / (den + 1e-10f);
  float4 r;
  if (half == 0) r = make_float4(ax * inv, ay * inv, az * inv, aw * inv);
  else           r = make_float4(bx * inv, by * inv, bz * inv, bw * inv);
  *(float4*)(out + (size_t)d * HF + li * 8 + half * 4) = r;
}

extern "C" void kernel_launch(void* const* d_in, const int* in_sizes, int n_in,
                              void* d_out, int out_size, void* d_ws, size_t ws_size,
                              hipStream_t stream) {
  const float* x     = (const float*)d_in[0];
  const int*   ei    = (const int*)d_in[1];
  const float* ew    = (const float*)d_in[2];
  const float* W     = (const float*)d_in[3];
  const float* a_src = (const float*)d_in[4];
  const float* a_dst = (const float*)d_in[5];
  float* out = (float*)d_out;

  // workspace: hb | xb | wb | as | ad | deg | excl | row_start | cursor | rec | bsum | gmax
  unsigned short* hb = (unsigned short*)d_ws;            // 25.6 MB
  unsigned short* xb = hb + (size_t)N_NODES * HF;        // 25.6 MB
  unsigned short* wbp = xb + (size_t)N_NODES * IN_F;     // 131 KB
  float* as = (float*)(wbp + 65536);                     // [node][4]
  float* ad = as + (size_t)HEADS * N_NODES;              // [node][4]
  int* deg       = (int*)(ad + (size_t)HEADS * N_NODES);
  int* excl      = deg + N_NODES;
  int* row_start = excl + N_NODES;
  int* cursor    = row_start + N_NODES;
  int2* rec      = (int2*)(cursor + N_NODES);            // 6.4 MB
  int* bsum      = (int*)(rec + N_EDGES);                // 2048 ints (both paths)
  unsigned* gmax = (unsigned*)(bsum + 2048);

  const int* srcp = ei;
  const int* dstp = ei + N_EDGES;

  // Cooperative capacity: query once, cache. -1 => use fallback path.
  static int coopBlocks = -2;
  if (coopBlocks == -2) {
    int perCU = 0;
    hipError_t e = hipOccupancyMaxActiveBlocksPerMultiprocessor(&perCU, k_all, 256, 0);
    if (e == hipSuccess && perCU > 0) {
      int cap = perCU * 256;  // 256 CUs on MI355X
      coopBlocks = cap < 1024 ? cap : 1024;
    } else {
      coopBlocks = -1;
    }
  }

  bool done = false;
  if (coopBlocks > 0) {
    void* args[] = {
      (void*)&x, (void*)&srcp, (void*)&dstp, (void*)&ew, (void*)&W,
      (void*)&a_src, (void*)&a_dst, (void*)&xb, (void*)&wbp, (void*)&hb,
      (void*)&as, (void*)&ad, (void*)&deg, (void*)&row_start, (void*)&cursor,
      (void*)&rec, (void*)&bsum, (void*)&gmax, (void*)&out};
    hipError_t err = hipLaunchCooperativeKernel((void*)k_all, dim3(coopBlocks),
                                                dim3(256), args, 0, stream);
    if (err == hipSuccess) {
      done = true;
    } else {
      coopBlocks = -1;  // never retry cooperative in this process
    }
  }

  if (!done) {
    const int NB = (N_NODES + 255) / 256;  // 196
    k_pack_w<<<256, 256, 0, stream>>>(W, wbp, deg, gmax);
    k_pack_x<<<6250, 256, 0, stream>>>(x, xb);
    k_gemm<<<782, 256, 0, stream>>>(xb, wbp, a_src, a_dst, hb, as, ad);
    k_edge_max<<<N_EDGES / 256, 256, 0, stream>>>(srcp, dstp, ew, as, ad, gmax, deg);
    k_scan1<<<NB, 256, 0, stream>>>(deg, excl, bsum);
    k_scan2<<<1, 256, 0, stream>>>(bsum, NB);
    k_scan3<<<NB, 256, 0, stream>>>(excl, bsum, row_start, cursor);
    k_scatter<<<N_EDGES / 256, 256, 0, stream>>>(srcp, dstp, ew, cursor, rec);
    k_agg<<<N_NODES / 4, 256, 0, stream>>>(row_start, deg, rec, as, ad, gmax, hb, out);
  }
}

// Round 8
// 507.396 us; speedup vs baseline: 2.1397x; 2.1397x over previous
//
#include <hip/hip_runtime.h>

#define N_NODES 50000
#define N_EDGES 800000
#define IN_F 256
#define OUT_F 64
#define HEADS 4
#define HF 256  // HEADS*OUT_F
#define NEG_SLOPE 0.2f

typedef __bf16 bf16x8 __attribute__((ext_vector_type(8)));
typedef float f32x4 __attribute__((ext_vector_type(4)));

// ---- monotone float<->uint encoding for atomicMax on floats ----
__device__ __forceinline__ unsigned encf(float f) {
  unsigned u = __float_as_uint(f);
  return (u & 0x80000000u) ? ~u : (u | 0x80000000u);
}
__device__ __forceinline__ float decf(unsigned k) {
  unsigned u = (k & 0x80000000u) ? (k & 0x7FFFFFFFu) : ~k;
  return __uint_as_float(u);
}
// fp32 -> bf16 (round-to-nearest-even)
__device__ __forceinline__ unsigned short f2bf(float f) {
  unsigned u = __float_as_uint(f);
  u += 0x7FFFu + ((u >> 16) & 1u);
  return (unsigned short)(u >> 16);
}
__device__ __forceinline__ float bflo(unsigned u) { return __uint_as_float(u << 16); }
__device__ __forceinline__ float bfhi(unsigned u) { return __uint_as_float(u & 0xFFFF0000u); }

// ---- Kernel 1: fused prep. pack x (f32->bf16, 1.6M threads = the grid
// sizer), pack W (first 65536), dst-degree histogram (first 800K), zero
// gmax. All independent -> one dispatch.
__global__ __launch_bounds__(256) void k_prep(const float* __restrict__ x,
                                              const float* __restrict__ W,
                                              const int* __restrict__ dst,
                                              unsigned short* __restrict__ xb,
                                              unsigned short* __restrict__ wb,
                                              int* __restrict__ deg,
                                              unsigned* __restrict__ gmax) {
  int tid = blockIdx.x * 256 + threadIdx.x;  // 6250*256 = 1.6M
  // pack x: 8 floats per thread
  {
    const float* px = x + (size_t)tid * 8;
    float4 v0 = *(const float4*)px;
    float4 v1 = *(const float4*)(px + 4);
    uint4 o;
    o.x = (unsigned)f2bf(v0.x) | ((unsigned)f2bf(v0.y) << 16);
    o.y = (unsigned)f2bf(v0.z) | ((unsigned)f2bf(v0.w) << 16);
    o.z = (unsigned)f2bf(v1.x) | ((unsigned)f2bf(v1.y) << 16);
    o.w = (unsigned)f2bf(v1.z) | ((unsigned)f2bf(v1.w) << 16);
    *(uint4*)(xb + (size_t)tid * 8) = o;
  }
  // degree histogram (deg pre-zeroed by memset)
  if (tid < N_EDGES) atomicAdd(deg + dst[tid], 1);
  // pack W
  if (tid < 65536) {
    int j = tid & 7, l = (tid >> 3) & 63, kt = (tid >> 9) & 7;
    int w = (tid >> 12) & 3, hd = (tid >> 14) & 3;
    int k = kt * 32 + (l >> 4) * 8 + j;
    int o = w * 16 + (l & 15);
    wb[tid] = f2bf(W[((size_t)hd * IN_F + k) * OUT_F + o]);
  }
  if (tid == 0) *gmax = 0u;
}

// ---- Kernel 2: MFMA GEMM h = xb@W (bf16 in, fp32 acc), 783 blocks.
// Blocks 0..781: 64 rows x ALL 256 cols; wave w owns head w (4x4 C-frags,
// 128 MFMAs). Block 782: serial-carry scan of deg[50000] -> row_start,
// cursor (independent of gemm work; hidden under the other 782 blocks).
__global__ __launch_bounds__(256) void k_gemm(const unsigned short* __restrict__ xb,
                                              const unsigned short* __restrict__ wb,
                                              const float* __restrict__ a_src,
                                              const float* __restrict__ a_dst,
                                              unsigned short* __restrict__ hb,
                                              float* __restrict__ as_out,
                                              float* __restrict__ ad_out,
                                              const int* __restrict__ deg,
                                              int* __restrict__ row_start,
                                              int* __restrict__ cursor) {
  const int t = threadIdx.x;
  const int blk = blockIdx.x;
  const int wv = t >> 6, lane = t & 63;

  if (blk == 782) {
    // ---- scan block: exclusive prefix sum, one pass, serial carry ----
    __shared__ int wsum[4];
    int carry = 0;
    for (int base = 0; base < N_NODES; base += 256) {
      int i = base + t;
      int orig = (i < N_NODES) ? deg[i] : 0;
      int v = orig;
#pragma unroll
      for (int s = 1; s < 64; s <<= 1) {
        int u = __shfl_up(v, s);
        if (lane >= s) v += u;
      }
      if (lane == 63) wsum[wv] = v;
      __syncthreads();
      int wb_ = 0;
      for (int w2 = 0; w2 < wv; w2++) wb_ += wsum[w2];
      int tot = wsum[0] + wsum[1] + wsum[2] + wsum[3];
      if (i < N_NODES) {
        int rs = carry + wb_ + v - orig;
        row_start[i] = rs;
        cursor[i] = rs;
      }
      carry += tot;
      __syncthreads();
    }
    return;
  }

  const int hd = wv, quad = lane >> 4, col = lane & 15;
  f32x4 acc[4][4];
#pragma unroll
  for (int ms = 0; ms < 4; ms++)
#pragma unroll
    for (int nt = 0; nt < 4; nt++) acc[ms][nt] = (f32x4){0.f, 0.f, 0.f, 0.f};

  const unsigned short* ab[4];
#pragma unroll
  for (int ms = 0; ms < 4; ms++) {
    int mt = blk * 4 + ms;
    if (mt > 3124) mt = 3124;  // tail: dup compute, stores guarded by m<N
    ab[ms] = xb + (size_t)(mt * 16 + col) * IN_F + quad * 8;
  }
  const unsigned short* wbase = wb + (size_t)hd * 16384 + lane * 8;

  for (int kt = 0; kt < 8; kt++) {
    union { uint4 u; bf16x8 v; } b[4], a[4];
#pragma unroll
    for (int nt = 0; nt < 4; nt++)
      b[nt].u = *(const uint4*)(wbase + (nt * 8 + kt) * 512);
#pragma unroll
    for (int ms = 0; ms < 4; ms++)
      a[ms].u = *(const uint4*)(ab[ms] + kt * 32);
#pragma unroll
    for (int ms = 0; ms < 4; ms++)
#pragma unroll
      for (int nt = 0; nt < 4; nt++)
        acc[ms][nt] = __builtin_amdgcn_mfma_f32_16x16x32_bf16(a[ms].v, b[nt].v, acc[ms][nt], 0, 0, 0);
  }

  // C/D layout: col = lane&15, row = quad*4 + r  [verified m89/m91]
  float avs[4], avd[4];
#pragma unroll
  for (int nt = 0; nt < 4; nt++) {
    avs[nt] = a_src[hd * OUT_F + nt * 16 + col];
    avd[nt] = a_dst[hd * OUT_F + nt * 16 + col];
  }
#pragma unroll
  for (int ms = 0; ms < 4; ms++) {
    int mbase = blk * 64 + ms * 16 + quad * 4;
#pragma unroll
    for (int r = 0; r < 4; r++) {
      int m = mbase + r;
      float ps = 0.f, pd = 0.f;
#pragma unroll
      for (int nt = 0; nt < 4; nt++) {
        float hv = acc[ms][nt][r];
        if (m < N_NODES)
          hb[(size_t)m * HF + hd * OUT_F + nt * 16 + col] = f2bf(hv);
        ps += hv * avs[nt];
        pd += hv * avd[nt];
      }
#pragma unroll
      for (int off = 8; off > 0; off >>= 1) {
        ps += __shfl_down(ps, off, 16);
        pd += __shfl_down(pd, off, 16);
      }
      if (col == 0 && m < N_NODES) {
        as_out[m * 4 + hd] = ps;   // [node][head] interleaved
        ad_out[m * 4 + hd] = pd;
      }
    }
  }
}

// ---- Kernel 3: counting-sort scatter FUSED with global edge max.
// Per edge: gather as4[s]/ad4[d] (16B each), 4-head max -> wave-reduced
// atomicMax(gmax); atomic cursor bump -> rec write.
__global__ __launch_bounds__(256) void k_scatter_max(const int* __restrict__ src,
                                                     const int* __restrict__ dst,
                                                     const float* __restrict__ ew,
                                                     const float* __restrict__ as,
                                                     const float* __restrict__ ad,
                                                     int* __restrict__ cursor,
                                                     int2* __restrict__ rec,
                                                     unsigned* __restrict__ gmax) {
  int e = blockIdx.x * 256 + threadIdx.x;
  int s = src[e], d = dst[e];
  float w = ew[e];
  float4 a = *(const float4*)(as + (size_t)s * 4);
  float4 b = *(const float4*)(ad + (size_t)d * 4);
  float v0 = a.x + b.x, v1 = a.y + b.y, v2 = a.z + b.z, v3 = a.w + b.w;
  v0 = v0 >= 0.f ? v0 : NEG_SLOPE * v0;
  v1 = v1 >= 0.f ? v1 : NEG_SLOPE * v1;
  v2 = v2 >= 0.f ? v2 : NEG_SLOPE * v2;
  v3 = v3 >= 0.f ? v3 : NEG_SLOPE * v3;
  float m = fmaxf(fmaxf(v0 * w, v1 * w), fmaxf(v2 * w, v3 * w));
#pragma unroll
  for (int off = 32; off > 0; off >>= 1) m = fmaxf(m, __shfl_down(m, off));
  if ((threadIdx.x & 63) == 0) atomicMax(gmax, encf(m));
  int pos = atomicAdd(cursor + d, 1);
  rec[pos] = make_int2(s, __float_as_int(w));
}

// ---- Kernel 4: wave-autonomous aggregation (unchanged, verified). One dst
// node per WAVE, zero __syncthreads. 8 edges/step, 4 uint4 gathers in flight.
__global__ __launch_bounds__(256) void k_agg(const int* __restrict__ row_start,
                                             const int* __restrict__ deg,
                                             const int2* __restrict__ rec,
                                             const float* __restrict__ as,
                                             const float* __restrict__ ad,
                                             const unsigned* __restrict__ gmax,
                                             const unsigned short* __restrict__ hb,
                                             float* __restrict__ out) {
  __shared__ float sal[4][4][68];  // [wave][head][edge-in-chunk], padded
  const int t = threadIdx.x;
  const int wv = t >> 6, lane = t & 63;
  const int half = lane >> 5, li = lane & 31;
  const int hd8 = li >> 3;
  const int d = blockIdx.x * 4 + wv;       // 12500*4 == 50000 exactly
  const int rs = row_start[d];
  const int dg = deg[d];
  const float gm = decf(*gmax);
  const float4 adv = *(const float4*)(ad + (size_t)d * 4);
  float ax = 0.f, ay = 0.f, az = 0.f, aw = 0.f;
  float bx = 0.f, by = 0.f, bz = 0.f, bw = 0.f;
  float den = 0.f;

  for (int j0 = 0; j0 < dg; j0 += 64) {
    const int nj = min(64, dg - j0);
    int se = 0;
    float we = 0.f;
    if (lane < nj) {
      int2 r = rec[rs + j0 + lane];
      se = r.x;
      we = __int_as_float(r.y);
    }
    {
      float4 a4 = *(const float4*)(as + (size_t)se * 4);
      float v0 = a4.x + adv.x;
      float v1 = a4.y + adv.y;
      float v2 = a4.z + adv.z;
      float v3 = a4.w + adv.w;
      v0 = v0 >= 0.f ? v0 : NEG_SLOPE * v0;
      v1 = v1 >= 0.f ? v1 : NEG_SLOPE * v1;
      v2 = v2 >= 0.f ? v2 : NEG_SLOPE * v2;
      v3 = v3 >= 0.f ? v3 : NEG_SLOPE * v3;
      bool ok = lane < nj;
      sal[wv][0][lane] = ok ? __expf(v0 * we - gm) : 0.f;
      sal[wv][1][lane] = ok ? __expf(v1 * we - gm) : 0.f;
      sal[wv][2][lane] = ok ? __expf(v2 * we - gm) : 0.f;
      sal[wv][3][lane] = ok ? __expf(v3 * we - gm) : 0.f;
    }
    // wave-local fence: ds_writes complete before cross-lane reads
    asm volatile("s_waitcnt lgkmcnt(0)" ::: "memory");
    const float* salh = sal[wv][hd8];

    int j = 0;
    for (; j + 7 < nj; j += 8) {
      int sj0 = __shfl(se, j + half);
      int sj1 = __shfl(se, j + 2 + half);
      int sj2 = __shfl(se, j + 4 + half);
      int sj3 = __shfl(se, j + 6 + half);
      uint4 q0 = *(const uint4*)(hb + (size_t)sj0 * HF + li * 8);
      uint4 q1 = *(const uint4*)(hb + (size_t)sj1 * HF + li * 8);
      uint4 q2 = *(const uint4*)(hb + (size_t)sj2 * HF + li * 8);
      uint4 q3 = *(const uint4*)(hb + (size_t)sj3 * HF + li * 8);
      float a0 = salh[j + half];
      float a1 = salh[j + 2 + half];
      float a2 = salh[j + 4 + half];
      float a3 = salh[j + 6 + half];
      den += (a0 + a1) + (a2 + a3);
      ax += a0 * bflo(q0.x) + a1 * bflo(q1.x) + a2 * bflo(q2.x) + a3 * bflo(q3.x);
      ay += a0 * bfhi(q0.x) + a1 * bfhi(q1.x) + a2 * bfhi(q2.x) + a3 * bfhi(q3.x);
      az += a0 * bflo(q0.y) + a1 * bflo(q1.y) + a2 * bflo(q2.y) + a3 * bflo(q3.y);
      aw += a0 * bfhi(q0.y) + a1 * bfhi(q1.y) + a2 * bfhi(q2.y) + a3 * bfhi(q3.y);
      bx += a0 * bflo(q0.z) + a1 * bflo(q1.z) + a2 * bflo(q2.z) + a3 * bflo(q3.z);
      by += a0 * bfhi(q0.z) + a1 * bfhi(q1.z) + a2 * bfhi(q2.z) + a3 * bfhi(q3.z);
      bz += a0 * bflo(q0.w) + a1 * bflo(q1.w) + a2 * bflo(q2.w) + a3 * bflo(q3.w);
      bw += a0 * bfhi(q0.w) + a1 * bfhi(q1.w) + a2 * bfhi(q2.w) + a3 * bfhi(q3.w);
    }
    for (; j < nj; j += 2) {
      int sj0 = __shfl(se, min(j + half, nj - 1));
      float a0 = (j + half < nj) ? salh[j + half] : 0.f;
      uint4 q0 = *(const uint4*)(hb + (size_t)sj0 * HF + li * 8);
      den += a0;
      ax += a0 * bflo(q0.x);
      ay += a0 * bfhi(q0.x);
      az += a0 * bflo(q0.y);
      aw += a0 * bfhi(q0.y);
      bx += a0 * bflo(q0.z);
      by += a0 * bfhi(q0.z);
      bz += a0 * bflo(q0.w);
      bw += a0 * bfhi(q0.w);
    }
  }

  // combine the two edge-halves (lane l <-> l^32 hold same columns)
  ax += __shfl_xor(ax, 32); ay += __shfl_xor(ay, 32);
  az += __shfl_xor(az, 32); aw += __shfl_xor(aw, 32);
  bx += __shfl_xor(bx, 32); by += __shfl_xor(by, 32);
  bz += __shfl_xor(bz, 32); bw += __shfl_xor(bw, 32);
  den += __shfl_xor(den, 32);
  float inv = 1.f / (den + 1e-10f);
  float4 r;
  if (half == 0) r = make_float4(ax * inv, ay * inv, az * inv, aw * inv);
  else           r = make_float4(bx * inv, by * inv, bz * inv, bw * inv);
  *(float4*)(out + (size_t)d * HF + li * 8 + half * 4) = r;
}

extern "C" void kernel_launch(void* const* d_in, const int* in_sizes, int n_in,
                              void* d_out, int out_size, void* d_ws, size_t ws_size,
                              hipStream_t stream) {
  const float* x     = (const float*)d_in[0];
  const int*   ei    = (const int*)d_in[1];
  const float* ew    = (const float*)d_in[2];
  const float* W     = (const float*)d_in[3];
  const float* a_src = (const float*)d_in[4];
  const float* a_dst = (const float*)d_in[5];
  float* out = (float*)d_out;

  // workspace: hb | xb | wb | as | ad | deg | row_start | cursor | rec | gmax
  unsigned short* hb = (unsigned short*)d_ws;            // 25.6 MB
  unsigned short* xb = hb + (size_t)N_NODES * HF;        // 25.6 MB
  unsigned short* wbp = xb + (size_t)N_NODES * IN_F;     // 131 KB
  float* as = (float*)(wbp + 65536);                     // [node][4]
  float* ad = as + (size_t)HEADS * N_NODES;              // [node][4]
  int* deg       = (int*)(ad + (size_t)HEADS * N_NODES);
  int* row_start = deg + N_NODES;
  int* cursor    = row_start + N_NODES;
  int2* rec      = (int2*)(cursor + N_NODES);            // 6.4 MB
  unsigned* gmax = (unsigned*)(rec + N_EDGES);

  const int* srcp = ei;
  const int* dstp = ei + N_EDGES;

  hipMemsetAsync(deg, 0, (size_t)N_NODES * sizeof(int), stream);
  k_prep<<<6250, 256, 0, stream>>>(x, W, dstp, xb, wbp, deg, gmax);
  k_gemm<<<783, 256, 0, stream>>>(xb, wbp, a_src, a_dst, hb, as, ad,
                                  deg, row_start, cursor);
  k_scatter_max<<<N_EDGES / 256, 256, 0, stream>>>(srcp, dstp, ew, as, ad,
                                                   cursor, rec, gmax);
  k_agg<<<N_NODES / 4, 256, 0, stream>>>(row_start, deg, rec, as, ad, gmax, hb, out);
}

// Round 9
// 286.341 us; speedup vs baseline: 3.7915x; 1.7720x over previous
//
#include <hip/hip_runtime.h>

#define N_NODES 50000
#define N_EDGES 800000
#define IN_F 256
#define OUT_F 64
#define HEADS 4
#define HF 256  // HEADS*OUT_F
#define NEG_SLOPE 0.2f

typedef __bf16 bf16x8 __attribute__((ext_vector_type(8)));
typedef float f32x4 __attribute__((ext_vector_type(4)));

// ---- monotone float<->uint encoding for atomicMax on floats ----
__device__ __forceinline__ unsigned encf(float f) {
  unsigned u = __float_as_uint(f);
  return (u & 0x80000000u) ? ~u : (u | 0x80000000u);
}
__device__ __forceinline__ float decf(unsigned k) {
  unsigned u = (k & 0x80000000u) ? (k & 0x7FFFFFFFu) : ~k;
  return __uint_as_float(u);
}
// fp32 -> bf16 (round-to-nearest-even)
__device__ __forceinline__ unsigned short f2bf(float f) {
  unsigned u = __float_as_uint(f);
  u += 0x7FFFu + ((u >> 16) & 1u);
  return (unsigned short)(u >> 16);
}
__device__ __forceinline__ float bflo(unsigned u) { return __uint_as_float(u << 16); }
__device__ __forceinline__ float bfhi(unsigned u) { return __uint_as_float(u & 0xFFFF0000u); }

// ---- Kernel 1: fused prep. pack x (f32->bf16, 1.6M threads = grid sizer),
// pack W (first 65536 threads), dst-degree histogram (first 800K threads).
// deg/alloc/gmax pre-zeroed by one memset.
__global__ __launch_bounds__(256) void k_prep(const float* __restrict__ x,
                                              const float* __restrict__ W,
                                              const int* __restrict__ dst,
                                              unsigned short* __restrict__ xb,
                                              unsigned short* __restrict__ wb,
                                              int* __restrict__ deg) {
  int tid = blockIdx.x * 256 + threadIdx.x;  // 6250*256 = 1.6M
  {
    const float* px = x + (size_t)tid * 8;
    float4 v0 = *(const float4*)px;
    float4 v1 = *(const float4*)(px + 4);
    uint4 o;
    o.x = (unsigned)f2bf(v0.x) | ((unsigned)f2bf(v0.y) << 16);
    o.y = (unsigned)f2bf(v0.z) | ((unsigned)f2bf(v0.w) << 16);
    o.z = (unsigned)f2bf(v1.x) | ((unsigned)f2bf(v1.y) << 16);
    o.w = (unsigned)f2bf(v1.z) | ((unsigned)f2bf(v1.w) << 16);
    *(uint4*)(xb + (size_t)tid * 8) = o;
  }
  if (tid < N_EDGES) atomicAdd(deg + dst[tid], 1);
  if (tid < 65536) {
    int j = tid & 7, l = (tid >> 3) & 63, kt = (tid >> 9) & 7;
    int w = (tid >> 12) & 3, hd = (tid >> 14) & 3;
    int k = kt * 32 + (l >> 4) * 8 + j;
    int o = w * 16 + (l & 15);
    wb[tid] = f2bf(W[((size_t)hd * IN_F + k) * OUT_F + o]);
  }
}

// ---- Kernel 2: MFMA GEMM h = xb@W (bf16 in, fp32 acc), pure 782 blocks.
// Block = 64 rows x ALL 256 cols; wave w owns head w (4x4 C-frags, 128 MFMAs).
__global__ __launch_bounds__(256) void k_gemm(const unsigned short* __restrict__ xb,
                                              const unsigned short* __restrict__ wb,
                                              const float* __restrict__ a_src,
                                              const float* __restrict__ a_dst,
                                              unsigned short* __restrict__ hb,
                                              float* __restrict__ as_out,
                                              float* __restrict__ ad_out) {
  const int t = threadIdx.x;
  const int hd = t >> 6, l = t & 63;
  const int quad = l >> 4, col = l & 15;
  const int blk = blockIdx.x;
  f32x4 acc[4][4];
#pragma unroll
  for (int ms = 0; ms < 4; ms++)
#pragma unroll
    for (int nt = 0; nt < 4; nt++) acc[ms][nt] = (f32x4){0.f, 0.f, 0.f, 0.f};

  const unsigned short* ab[4];
#pragma unroll
  for (int ms = 0; ms < 4; ms++) {
    int mt = blk * 4 + ms;
    if (mt > 3124) mt = 3124;  // tail: dup compute, stores guarded by m<N
    ab[ms] = xb + (size_t)(mt * 16 + col) * IN_F + quad * 8;
  }
  const unsigned short* wbase = wb + (size_t)hd * 16384 + l * 8;

  for (int kt = 0; kt < 8; kt++) {
    union { uint4 u; bf16x8 v; } b[4], a[4];
#pragma unroll
    for (int nt = 0; nt < 4; nt++)
      b[nt].u = *(const uint4*)(wbase + (nt * 8 + kt) * 512);
#pragma unroll
    for (int ms = 0; ms < 4; ms++)
      a[ms].u = *(const uint4*)(ab[ms] + kt * 32);
#pragma unroll
    for (int ms = 0; ms < 4; ms++)
#pragma unroll
      for (int nt = 0; nt < 4; nt++)
        acc[ms][nt] = __builtin_amdgcn_mfma_f32_16x16x32_bf16(a[ms].v, b[nt].v, acc[ms][nt], 0, 0, 0);
  }

  // C/D layout: col = lane&15, row = quad*4 + r  [verified m89/m91]
  float avs[4], avd[4];
#pragma unroll
  for (int nt = 0; nt < 4; nt++) {
    avs[nt] = a_src[hd * OUT_F + nt * 16 + col];
    avd[nt] = a_dst[hd * OUT_F + nt * 16 + col];
  }
#pragma unroll
  for (int ms = 0; ms < 4; ms++) {
    int mbase = blk * 64 + ms * 16 + quad * 4;
#pragma unroll
    for (int r = 0; r < 4; r++) {
      int m = mbase + r;
      float ps = 0.f, pd = 0.f;
#pragma unroll
      for (int nt = 0; nt < 4; nt++) {
        float hv = acc[ms][nt][r];
        if (m < N_NODES)
          hb[(size_t)m * HF + hd * OUT_F + nt * 16 + col] = f2bf(hv);
        ps += hv * avs[nt];
        pd += hv * avd[nt];
      }
#pragma unroll
      for (int off = 8; off > 0; off >>= 1) {
        ps += __shfl_down(ps, off, 16);
        pd += __shfl_down(pd, off, 16);
      }
      if (col == 0 && m < N_NODES) {
        as_out[m * 4 + hd] = ps;   // [node][head] interleaved
        ad_out[m * 4 + hd] = pd;
      }
    }
  }
}

// ---- Kernel 3: one-dispatch ORDER-FREE scan. agg only needs disjoint
// contiguous per-dst ranges, not node-id-ordered offsets. Each block scans
// its 256 nodes locally, grabs a global base via ONE atomicAdd(alloc).
__global__ __launch_bounds__(256) void k_alloc_scan(const int* __restrict__ deg,
                                                    int* __restrict__ alloc,
                                                    int* __restrict__ row_start,
                                                    int* __restrict__ cursor) {
  int i = blockIdx.x * 256 + threadIdx.x;
  int lane = threadIdx.x & 63, wv = threadIdx.x >> 6;
  int orig = (i < N_NODES) ? deg[i] : 0;
  int v = orig;
#pragma unroll
  for (int s = 1; s < 64; s <<= 1) {
    int u = __shfl_up(v, s);
    if (lane >= s) v += u;
  }
  __shared__ int wsum[4];
  __shared__ int sbase;
  if (lane == 63) wsum[wv] = v;
  __syncthreads();
  int base = 0;
  for (int w = 0; w < wv; w++) base += wsum[w];
  if (threadIdx.x == 0)
    sbase = atomicAdd(alloc, wsum[0] + wsum[1] + wsum[2] + wsum[3]);
  __syncthreads();
  if (i < N_NODES) {
    int rs = sbase + base + v - orig;
    row_start[i] = rs;
    cursor[i] = rs;
  }
}

// ---- Kernel 4: counting-sort scatter fused with global edge max.
// FIXED vs R8: 2 edges/thread (int2/float2 coalesced loads); cursor atomics
// + rec stores issued BEFORE the gather-dependent max code so the three
// latency chains (atomic, gathers, store) overlap; per-BLOCK atomicMax.
__global__ __launch_bounds__(256) void k_scatter_max(const int* __restrict__ src,
                                                     const int* __restrict__ dst,
                                                     const float* __restrict__ ew,
                                                     const float* __restrict__ as,
                                                     const float* __restrict__ ad,
                                                     int* __restrict__ cursor,
                                                     int2* __restrict__ rec,
                                                     unsigned* __restrict__ gmax) {
  int t2 = blockIdx.x * 256 + threadIdx.x;  // pair index, < 400128
  bool ok = t2 * 2 < N_EDGES;               // pairs are whole (800000 even)
  int2 s2 = ok ? *(const int2*)(src + t2 * 2) : make_int2(0, 0);
  int2 d2 = ok ? *(const int2*)(dst + t2 * 2) : make_int2(0, 0);
  float2 w2 = ok ? *(const float2*)(ew + t2 * 2) : make_float2(0.f, 0.f);

  // latency chain 1: cursor atomics + rec stores (independent of gathers)
  int pos0 = 0, pos1 = 0;
  if (ok) {
    pos0 = atomicAdd(cursor + d2.x, 1);
    pos1 = atomicAdd(cursor + d2.y, 1);
  }
  // latency chain 2: logit gathers (issued while atomics are in flight)
  float4 a0, b0, a1, b1;
  if (ok) {
    a0 = *(const float4*)(as + (size_t)s2.x * 4);
    b0 = *(const float4*)(ad + (size_t)d2.x * 4);
    a1 = *(const float4*)(as + (size_t)s2.y * 4);
    b1 = *(const float4*)(ad + (size_t)d2.y * 4);
  } else {
    a0 = b0 = a1 = b1 = make_float4(0.f, 0.f, 0.f, 0.f);
  }
  if (ok) {
    rec[pos0] = make_int2(s2.x, __float_as_int(w2.x));
    rec[pos1] = make_int2(s2.y, __float_as_int(w2.y));
  }

  float m = -3.4e38f;
  if (ok) {
    float v0 = a0.x + b0.x, v1 = a0.y + b0.y, v2 = a0.z + b0.z, v3 = a0.w + b0.w;
    v0 = v0 >= 0.f ? v0 : NEG_SLOPE * v0;
    v1 = v1 >= 0.f ? v1 : NEG_SLOPE * v1;
    v2 = v2 >= 0.f ? v2 : NEG_SLOPE * v2;
    v3 = v3 >= 0.f ? v3 : NEG_SLOPE * v3;
    m = fmaxf(fmaxf(v0 * w2.x, v1 * w2.x), fmaxf(v2 * w2.x, v3 * w2.x));
    float u0 = a1.x + b1.x, u1 = a1.y + b1.y, u2 = a1.z + b1.z, u3 = a1.w + b1.w;
    u0 = u0 >= 0.f ? u0 : NEG_SLOPE * u0;
    u1 = u1 >= 0.f ? u1 : NEG_SLOPE * u1;
    u2 = u2 >= 0.f ? u2 : NEG_SLOPE * u2;
    u3 = u3 >= 0.f ? u3 : NEG_SLOPE * u3;
    m = fmaxf(m, fmaxf(fmaxf(u0 * w2.y, u1 * w2.y), fmaxf(u2 * w2.y, u3 * w2.y)));
  }
#pragma unroll
  for (int off = 32; off > 0; off >>= 1) m = fmaxf(m, __shfl_down(m, off));
  __shared__ float red[4];
  int wave = threadIdx.x >> 6, lane = threadIdx.x & 63;
  if (lane == 0) red[wave] = m;
  __syncthreads();
  if (threadIdx.x == 0) {
    float mm = fmaxf(fmaxf(red[0], red[1]), fmaxf(red[2], red[3]));
    atomicMax(gmax, encf(mm));
  }
}

// ---- Kernel 5: wave-autonomous aggregation (unchanged, verified). One dst
// node per WAVE, zero __syncthreads. 8 edges/step, 4 uint4 gathers in flight.
__global__ __launch_bounds__(256) void k_agg(const int* __restrict__ row_start,
                                             const int* __restrict__ deg,
                                             const int2* __restrict__ rec,
                                             const float* __restrict__ as,
                                             const float* __restrict__ ad,
                                             const unsigned* __restrict__ gmax,
                                             const unsigned short* __restrict__ hb,
                                             float* __restrict__ out) {
  __shared__ float sal[4][4][68];  // [wave][head][edge-in-chunk], padded
  const int t = threadIdx.x;
  const int wv = t >> 6, lane = t & 63;
  const int half = lane >> 5, li = lane & 31;
  const int hd8 = li >> 3;
  const int d = blockIdx.x * 4 + wv;       // 12500*4 == 50000 exactly
  const int rs = row_start[d];
  const int dg = deg[d];
  const float gm = decf(*gmax);
  const float4 adv = *(const float4*)(ad + (size_t)d * 4);
  float ax = 0.f, ay = 0.f, az = 0.f, aw = 0.f;
  float bx = 0.f, by = 0.f, bz = 0.f, bw = 0.f;
  float den = 0.f;

  for (int j0 = 0; j0 < dg; j0 += 64) {
    const int nj = min(64, dg - j0);
    int se = 0;
    float we = 0.f;
    if (lane < nj) {
      int2 r = rec[rs + j0 + lane];
      se = r.x;
      we = __int_as_float(r.y);
    }
    {
      float4 a4 = *(const float4*)(as + (size_t)se * 4);
      float v0 = a4.x + adv.x;
      float v1 = a4.y + adv.y;
      float v2 = a4.z + adv.z;
      float v3 = a4.w + adv.w;
      v0 = v0 >= 0.f ? v0 : NEG_SLOPE * v0;
      v1 = v1 >= 0.f ? v1 : NEG_SLOPE * v1;
      v2 = v2 >= 0.f ? v2 : NEG_SLOPE * v2;
      v3 = v3 >= 0.f ? v3 : NEG_SLOPE * v3;
      bool okj = lane < nj;
      sal[wv][0][lane] = okj ? __expf(v0 * we - gm) : 0.f;
      sal[wv][1][lane] = okj ? __expf(v1 * we - gm) : 0.f;
      sal[wv][2][lane] = okj ? __expf(v2 * we - gm) : 0.f;
      sal[wv][3][lane] = okj ? __expf(v3 * we - gm) : 0.f;
    }
    // wave-local fence: ds_writes complete before cross-lane reads
    asm volatile("s_waitcnt lgkmcnt(0)" ::: "memory");
    const float* salh = sal[wv][hd8];

    int j = 0;
    for (; j + 7 < nj; j += 8) {
      int sj0 = __shfl(se, j + half);
      int sj1 = __shfl(se, j + 2 + half);
      int sj2 = __shfl(se, j + 4 + half);
      int sj3 = __shfl(se, j + 6 + half);
      uint4 q0 = *(const uint4*)(hb + (size_t)sj0 * HF + li * 8);
      uint4 q1 = *(const uint4*)(hb + (size_t)sj1 * HF + li * 8);
      uint4 q2 = *(const uint4*)(hb + (size_t)sj2 * HF + li * 8);
      uint4 q3 = *(const uint4*)(hb + (size_t)sj3 * HF + li * 8);
      float a0 = salh[j + half];
      float a1 = salh[j + 2 + half];
      float a2 = salh[j + 4 + half];
      float a3 = salh[j + 6 + half];
      den += (a0 + a1) + (a2 + a3);
      ax += a0 * bflo(q0.x) + a1 * bflo(q1.x) + a2 * bflo(q2.x) + a3 * bflo(q3.x);
      ay += a0 * bfhi(q0.x) + a1 * bfhi(q1.x) + a2 * bfhi(q2.x) + a3 * bfhi(q3.x);
      az += a0 * bflo(q0.y) + a1 * bflo(q1.y) + a2 * bflo(q2.y) + a3 * bflo(q3.y);
      aw += a0 * bfhi(q0.y) + a1 * bfhi(q1.y) + a2 * bfhi(q2.y) + a3 * bfhi(q3.y);
      bx += a0 * bflo(q0.z) + a1 * bflo(q1.z) + a2 * bflo(q2.z) + a3 * bflo(q3.z);
      by += a0 * bfhi(q0.z) + a1 * bfhi(q1.z) + a2 * bfhi(q2.z) + a3 * bfhi(q3.z);
      bz += a0 * bflo(q0.w) + a1 * bflo(q1.w) + a2 * bflo(q2.w) + a3 * bflo(q3.w);
      bw += a0 * bfhi(q0.w) + a1 * bfhi(q1.w) + a2 * bfhi(q2.w) + a3 * bfhi(q3.w);
    }
    for (; j < nj; j += 2) {
      int sj0 = __shfl(se, min(j + half, nj - 1));
      float a0 = (j + half < nj) ? salh[j + half] : 0.f;
      uint4 q0 = *(const uint4*)(hb + (size_t)sj0 * HF + li * 8);
      den += a0;
      ax += a0 * bflo(q0.x);
      ay += a0 * bfhi(q0.x);
      az += a0 * bflo(q0.y);
      aw += a0 * bfhi(q0.y);
      bx += a0 * bflo(q0.z);
      by += a0 * bfhi(q0.z);
      bz += a0 * bflo(q0.w);
      bw += a0 * bfhi(q0.w);
    }
  }

  // combine the two edge-halves (lane l <-> l^32 hold same columns)
  ax += __shfl_xor(ax, 32); ay += __shfl_xor(ay, 32);
  az += __shfl_xor(az, 32); aw += __shfl_xor(aw, 32);
  bx += __shfl_xor(bx, 32); by += __shfl_xor(by, 32);
  bz += __shfl_xor(bz, 32); bw += __shfl_xor(bw, 32);
  den += __shfl_xor(den, 32);
  float inv = 1.f / (den + 1e-10f);
  float4 r;
  if (half == 0) r = make_float4(ax * inv, ay * inv, az * inv, aw * inv);
  else           r = make_float4(bx * inv, by * inv, bz * inv, bw * inv);
  *(float4*)(out + (size_t)d * HF + li * 8 + half * 4) = r;
}

extern "C" void kernel_launch(void* const* d_in, const int* in_sizes, int n_in,
                              void* d_out, int out_size, void* d_ws, size_t ws_size,
                              hipStream_t stream) {
  const float* x     = (const float*)d_in[0];
  const int*   ei    = (const int*)d_in[1];
  const float* ew    = (const float*)d_in[2];
  const float* W     = (const float*)d_in[3];
  const float* a_src = (const float*)d_in[4];
  const float* a_dst = (const float*)d_in[5];
  float* out = (float*)d_out;

  // workspace: hb | xb | wb | as | ad | [deg alloc gmax] | row_start | cursor | rec
  unsigned short* hb = (unsigned short*)d_ws;            // 25.6 MB
  unsigned short* xb = hb + (size_t)N_NODES * HF;        // 25.6 MB
  unsigned short* wbp = xb + (size_t)N_NODES * IN_F;     // 131 KB
  float* as = (float*)(wbp + 65536);                     // [node][4]
  float* ad = as + (size_t)HEADS * N_NODES;              // [node][4]
  int* deg       = (int*)(ad + (size_t)HEADS * N_NODES); // 50000
  int* alloc     = deg + N_NODES;                        // 1
  unsigned* gmax = (unsigned*)(alloc + 1);               // 1
  int* row_start = (int*)(gmax + 1);                     // 50000
  int* cursor    = row_start + N_NODES;                  // 50000
  int2* rec      = (int2*)(cursor + N_NODES);            // 6.4 MB

  const int* srcp = ei;
  const int* dstp = ei + N_EDGES;

  // one memset covers deg + alloc + gmax (contiguous)
  hipMemsetAsync(deg, 0, (size_t)(N_NODES + 2) * sizeof(int), stream);
  k_prep<<<6250, 256, 0, stream>>>(x, W, dstp, xb, wbp, deg);
  k_gemm<<<782, 256, 0, stream>>>(xb, wbp, a_src, a_dst, hb, as, ad);
  k_alloc_scan<<<(N_NODES + 255) / 256, 256, 0, stream>>>(deg, alloc, row_start, cursor);
  k_scatter_max<<<(N_EDGES / 2 + 255) / 256, 256, 0, stream>>>(srcp, dstp, ew, as, ad,
                                                               cursor, rec, gmax);
  k_agg<<<N_NODES / 4, 256, 0, stream>>>(row_start, deg, rec, as, ad, gmax, hb, out);
}

// Round 10
// 272.046 us; speedup vs baseline: 3.9908x; 1.0525x over previous
//
#include <hip/hip_runtime.h>

#define N_NODES 50000
#define N_EDGES 800000
#define IN_F 256
#define OUT_F 64
#define HEADS 4
#define HF 256  // HEADS*OUT_F
#define NEG_SLOPE 0.2f

typedef __bf16 bf16x8 __attribute__((ext_vector_type(8)));
typedef float f32x4 __attribute__((ext_vector_type(4)));

// ---- monotone float<->uint encoding for atomicMax on floats ----
__device__ __forceinline__ unsigned encf(float f) {
  unsigned u = __float_as_uint(f);
  return (u & 0x80000000u) ? ~u : (u | 0x80000000u);
}
__device__ __forceinline__ float decf(unsigned k) {
  unsigned u = (k & 0x80000000u) ? (k & 0x7FFFFFFFu) : ~k;
  return __uint_as_float(u);
}
// fp32 -> bf16 (round-to-nearest-even)
__device__ __forceinline__ unsigned short f2bf(float f) {
  unsigned u = __float_as_uint(f);
  u += 0x7FFFu + ((u >> 16) & 1u);
  return (unsigned short)(u >> 16);
}
__device__ __forceinline__ float bflo(unsigned u) { return __uint_as_float(u << 16); }
__device__ __forceinline__ float bfhi(unsigned u) { return __uint_as_float(u & 0xFFFF0000u); }

// ---- Kernel 0: init. Blocks 0..195 zero deg/alloc/gmax. Blocks 196..199
// (one per head) compute wa_src/wa_dst = W @ a_src / a_dst  (4 x 256 GEMV):
// as[m] = h[m]*a_src = x[m]*(W@a_src), so prep can emit logits from x in f32.
__global__ __launch_bounds__(256) void k_init(const float* __restrict__ W,
                                              const float* __restrict__ a_src,
                                              const float* __restrict__ a_dst,
                                              int* __restrict__ deg,
                                              int* __restrict__ alloc,
                                              unsigned* __restrict__ gmax,
                                              float* __restrict__ wa_src,
                                              float* __restrict__ wa_dst) {
  if (blockIdx.x < 196) {
    int i = blockIdx.x * 256 + threadIdx.x;
    if (i < N_NODES) deg[i] = 0;
    if (i == 0) { *alloc = 0; *gmax = 0u; }
    return;
  }
  int hd = blockIdx.x - 196;       // 0..3
  int k = threadIdx.x;             // 0..255
  const float* wrow = W + ((size_t)hd * IN_F + k) * OUT_F;  // 64 contiguous
  const float* asv = a_src + hd * OUT_F;
  const float* adv = a_dst + hd * OUT_F;
  float ss = 0.f, sd = 0.f;
#pragma unroll
  for (int o = 0; o < OUT_F; o += 4) {
    float4 w4 = *(const float4*)(wrow + o);
    float4 s4 = *(const float4*)(asv + o);
    float4 d4 = *(const float4*)(adv + o);
    ss += w4.x * s4.x + w4.y * s4.y + w4.z * s4.z + w4.w * s4.w;
    sd += w4.x * d4.x + w4.y * d4.y + w4.z * d4.z + w4.w * d4.w;
  }
  wa_src[hd * IN_F + k] = ss;
  wa_dst[hd * IN_F + k] = sd;
}

// ---- Kernel 1: fused prep. pack x (f32->bf16), pack W (first 65536),
// dst-degree histogram (first 800K), AND attn logits as/ad = x . wa
// (f32 dots, width-32 shfl reduce; row m = tid>>5 spans one half-wave).
__global__ __launch_bounds__(256) void k_prep(const float* __restrict__ x,
                                              const float* __restrict__ W,
                                              const int* __restrict__ dst,
                                              const float* __restrict__ wa_src,
                                              const float* __restrict__ wa_dst,
                                              unsigned short* __restrict__ xb,
                                              unsigned short* __restrict__ wb,
                                              int* __restrict__ deg,
                                              float* __restrict__ as,
                                              float* __restrict__ ad) {
  int tid = blockIdx.x * 256 + threadIdx.x;  // 6250*256 = 1.6M
  const float* px = x + (size_t)tid * 8;
  float4 v0 = *(const float4*)px;
  float4 v1 = *(const float4*)(px + 4);
  {
    uint4 o;
    o.x = (unsigned)f2bf(v0.x) | ((unsigned)f2bf(v0.y) << 16);
    o.y = (unsigned)f2bf(v0.z) | ((unsigned)f2bf(v0.w) << 16);
    o.z = (unsigned)f2bf(v1.x) | ((unsigned)f2bf(v1.y) << 16);
    o.w = (unsigned)f2bf(v1.z) | ((unsigned)f2bf(v1.w) << 16);
    *(uint4*)(xb + (size_t)tid * 8) = o;
  }
  if (tid < N_EDGES) atomicAdd(deg + dst[tid], 1);
  if (tid < 65536) {
    int j = tid & 7, l = (tid >> 3) & 63, kt = (tid >> 9) & 7;
    int w = (tid >> 12) & 3, hd = (tid >> 14) & 3;
    int k = kt * 32 + (l >> 4) * 8 + j;
    int o = w * 16 + (l & 15);
    wb[tid] = f2bf(W[((size_t)hd * IN_F + k) * OUT_F + o]);
  }
  // logits: row m = tid>>5, this thread covers cols k0..k0+7
  {
    int k0 = (tid & 31) * 8;
    float ps[4], pd[4];
#pragma unroll
    for (int hd = 0; hd < 4; hd++) {
      float4 s0 = *(const float4*)(wa_src + hd * IN_F + k0);
      float4 s1 = *(const float4*)(wa_src + hd * IN_F + k0 + 4);
      float4 d0 = *(const float4*)(wa_dst + hd * IN_F + k0);
      float4 d1 = *(const float4*)(wa_dst + hd * IN_F + k0 + 4);
      ps[hd] = v0.x * s0.x + v0.y * s0.y + v0.z * s0.z + v0.w * s0.w
             + v1.x * s1.x + v1.y * s1.y + v1.z * s1.z + v1.w * s1.w;
      pd[hd] = v0.x * d0.x + v0.y * d0.y + v0.z * d0.z + v0.w * d0.w
             + v1.x * d1.x + v1.y * d1.y + v1.z * d1.z + v1.w * d1.w;
    }
#pragma unroll
    for (int off = 16; off > 0; off >>= 1) {
#pragma unroll
      for (int hd = 0; hd < 4; hd++) {
        ps[hd] += __shfl_down(ps[hd], off, 32);
        pd[hd] += __shfl_down(pd[hd], off, 32);
      }
    }
    if ((tid & 31) == 0) {
      int m = tid >> 5;
      *(float4*)(as + (size_t)m * 4) = make_float4(ps[0], ps[1], ps[2], ps[3]);
      *(float4*)(ad + (size_t)m * 4) = make_float4(pd[0], pd[1], pd[2], pd[3]);
    }
  }
}

// ---- Kernel 2: one-dispatch ORDER-FREE scan (agg only needs disjoint
// contiguous per-dst ranges). Block-local scan + one atomicAdd(alloc).
__global__ __launch_bounds__(256) void k_alloc_scan(const int* __restrict__ deg,
                                                    int* __restrict__ alloc,
                                                    int* __restrict__ row_start,
                                                    int* __restrict__ cursor) {
  int i = blockIdx.x * 256 + threadIdx.x;
  int lane = threadIdx.x & 63, wv = threadIdx.x >> 6;
  int orig = (i < N_NODES) ? deg[i] : 0;
  int v = orig;
#pragma unroll
  for (int s = 1; s < 64; s <<= 1) {
    int u = __shfl_up(v, s);
    if (lane >= s) v += u;
  }
  __shared__ int wsum[4];
  __shared__ int sbase;
  if (lane == 63) wsum[wv] = v;
  __syncthreads();
  int base = 0;
  for (int w = 0; w < wv; w++) base += wsum[w];
  if (threadIdx.x == 0)
    sbase = atomicAdd(alloc, wsum[0] + wsum[1] + wsum[2] + wsum[3]);
  __syncthreads();
  if (i < N_NODES) {
    int rs = sbase + base + v - orig;
    row_start[i] = rs;
    cursor[i] = rs;
  }
}

// ---- Kernel 3: FUSED gemm + scatter_max (mutually independent; both need
// only prep+scan). Blocks 0..781: MFMA gemm (epilogue = hb stores only —
// logits moved to prep). Blocks 782..2344: counting-sort scatter + edge max
// (latency-bound; overlaps with gemm's compute-bound waves).
__global__ __launch_bounds__(256) void k_gemm_scatter(
    const unsigned short* __restrict__ xb, const unsigned short* __restrict__ wb,
    unsigned short* __restrict__ hb,
    const int* __restrict__ src, const int* __restrict__ dst,
    const float* __restrict__ ew, const float* __restrict__ as,
    const float* __restrict__ ad, int* __restrict__ cursor,
    int2* __restrict__ rec, unsigned* __restrict__ gmax) {
  const int t = threadIdx.x;

  if (blockIdx.x >= 782) {
    // ---------------- scatter + max path ----------------
    int t2 = (blockIdx.x - 782) * 256 + t;     // pair index, < 400128
    bool ok = t2 * 2 < N_EDGES;
    int2 s2 = ok ? *(const int2*)(src + t2 * 2) : make_int2(0, 0);
    int2 d2 = ok ? *(const int2*)(dst + t2 * 2) : make_int2(0, 0);
    float2 w2 = ok ? *(const float2*)(ew + t2 * 2) : make_float2(0.f, 0.f);
    int pos0 = 0, pos1 = 0;
    if (ok) {
      pos0 = atomicAdd(cursor + d2.x, 1);
      pos1 = atomicAdd(cursor + d2.y, 1);
    }
    float4 a0, b0, a1, b1;
    if (ok) {
      a0 = *(const float4*)(as + (size_t)s2.x * 4);
      b0 = *(const float4*)(ad + (size_t)d2.x * 4);
      a1 = *(const float4*)(as + (size_t)s2.y * 4);
      b1 = *(const float4*)(ad + (size_t)d2.y * 4);
    } else {
      a0 = b0 = a1 = b1 = make_float4(0.f, 0.f, 0.f, 0.f);
    }
    if (ok) {
      rec[pos0] = make_int2(s2.x, __float_as_int(w2.x));
      rec[pos1] = make_int2(s2.y, __float_as_int(w2.y));
    }
    float m = -3.4e38f;
    if (ok) {
      float v0 = a0.x + b0.x, v1 = a0.y + b0.y, v2 = a0.z + b0.z, v3 = a0.w + b0.w;
      v0 = v0 >= 0.f ? v0 : NEG_SLOPE * v0;
      v1 = v1 >= 0.f ? v1 : NEG_SLOPE * v1;
      v2 = v2 >= 0.f ? v2 : NEG_SLOPE * v2;
      v3 = v3 >= 0.f ? v3 : NEG_SLOPE * v3;
      m = fmaxf(fmaxf(v0 * w2.x, v1 * w2.x), fmaxf(v2 * w2.x, v3 * w2.x));
      float u0 = a1.x + b1.x, u1 = a1.y + b1.y, u2 = a1.z + b1.z, u3 = a1.w + b1.w;
      u0 = u0 >= 0.f ? u0 : NEG_SLOPE * u0;
      u1 = u1 >= 0.f ? u1 : NEG_SLOPE * u1;
      u2 = u2 >= 0.f ? u2 : NEG_SLOPE * u2;
      u3 = u3 >= 0.f ? u3 : NEG_SLOPE * u3;
      m = fmaxf(m, fmaxf(fmaxf(u0 * w2.y, u1 * w2.y), fmaxf(u2 * w2.y, u3 * w2.y)));
    }
#pragma unroll
    for (int off = 32; off > 0; off >>= 1) m = fmaxf(m, __shfl_down(m, off));
    __shared__ float red[4];
    int wave = t >> 6, lane = t & 63;
    if (lane == 0) red[wave] = m;
    __syncthreads();
    if (t == 0) {
      float mm = fmaxf(fmaxf(red[0], red[1]), fmaxf(red[2], red[3]));
      atomicMax(gmax, encf(mm));
    }
    return;
  }

  // ---------------- gemm path ----------------
  const int hd = t >> 6, l = t & 63;
  const int quad = l >> 4, col = l & 15;
  const int blk = blockIdx.x;
  f32x4 acc[4][4];
#pragma unroll
  for (int ms = 0; ms < 4; ms++)
#pragma unroll
    for (int nt = 0; nt < 4; nt++) acc[ms][nt] = (f32x4){0.f, 0.f, 0.f, 0.f};

  const unsigned short* ab[4];
#pragma unroll
  for (int ms = 0; ms < 4; ms++) {
    int mt = blk * 4 + ms;
    if (mt > 3124) mt = 3124;  // tail: dup compute, stores guarded by m<N
    ab[ms] = xb + (size_t)(mt * 16 + col) * IN_F + quad * 8;
  }
  const unsigned short* wbase = wb + (size_t)hd * 16384 + l * 8;

  for (int kt = 0; kt < 8; kt++) {
    union { uint4 u; bf16x8 v; } b[4], a[4];
#pragma unroll
    for (int nt = 0; nt < 4; nt++)
      b[nt].u = *(const uint4*)(wbase + (nt * 8 + kt) * 512);
#pragma unroll
    for (int ms = 0; ms < 4; ms++)
      a[ms].u = *(const uint4*)(ab[ms] + kt * 32);
#pragma unroll
    for (int ms = 0; ms < 4; ms++)
#pragma unroll
      for (int nt = 0; nt < 4; nt++)
        acc[ms][nt] = __builtin_amdgcn_mfma_f32_16x16x32_bf16(a[ms].v, b[nt].v, acc[ms][nt], 0, 0, 0);
  }

  // C/D layout: col = lane&15, row = quad*4 + r  [verified m89/m91]
#pragma unroll
  for (int ms = 0; ms < 4; ms++) {
    int mbase = blk * 64 + ms * 16 + quad * 4;
#pragma unroll
    for (int r = 0; r < 4; r++) {
      int m = mbase + r;
      if (m < N_NODES) {
#pragma unroll
        for (int nt = 0; nt < 4; nt++)
          hb[(size_t)m * HF + hd * OUT_F + nt * 16 + col] = f2bf(acc[ms][nt][r]);
      }
    }
  }
}

// ---- Kernel 4: wave-autonomous aggregation (unchanged, verified). One dst
// node per WAVE, zero __syncthreads. 8 edges/step, 4 uint4 gathers in flight.
__global__ __launch_bounds__(256) void k_agg(const int* __restrict__ row_start,
                                             const int* __restrict__ deg,
                                             const int2* __restrict__ rec,
                                             const float* __restrict__ as,
                                             const float* __restrict__ ad,
                                             const unsigned* __restrict__ gmax,
                                             const unsigned short* __restrict__ hb,
                                             float* __restrict__ out) {
  __shared__ float sal[4][4][68];  // [wave][head][edge-in-chunk], padded
  const int t = threadIdx.x;
  const int wv = t >> 6, lane = t & 63;
  const int half = lane >> 5, li = lane & 31;
  const int hd8 = li >> 3;
  const int d = blockIdx.x * 4 + wv;       // 12500*4 == 50000 exactly
  const int rs = row_start[d];
  const int dg = deg[d];
  const float gm = decf(*gmax);
  const float4 adv = *(const float4*)(ad + (size_t)d * 4);
  float ax = 0.f, ay = 0.f, az = 0.f, aw = 0.f;
  float bx = 0.f, by = 0.f, bz = 0.f, bw = 0.f;
  float den = 0.f;

  for (int j0 = 0; j0 < dg; j0 += 64) {
    const int nj = min(64, dg - j0);
    int se = 0;
    float we = 0.f;
    if (lane < nj) {
      int2 r = rec[rs + j0 + lane];
      se = r.x;
      we = __int_as_float(r.y);
    }
    {
      float4 a4 = *(const float4*)(as + (size_t)se * 4);
      float v0 = a4.x + adv.x;
      float v1 = a4.y + adv.y;
      float v2 = a4.z + adv.z;
      float v3 = a4.w + adv.w;
      v0 = v0 >= 0.f ? v0 : NEG_SLOPE * v0;
      v1 = v1 >= 0.f ? v1 : NEG_SLOPE * v1;
      v2 = v2 >= 0.f ? v2 : NEG_SLOPE * v2;
      v3 = v3 >= 0.f ? v3 : NEG_SLOPE * v3;
      bool okj = lane < nj;
      sal[wv][0][lane] = okj ? __expf(v0 * we - gm) : 0.f;
      sal[wv][1][lane] = okj ? __expf(v1 * we - gm) : 0.f;
      sal[wv][2][lane] = okj ? __expf(v2 * we - gm) : 0.f;
      sal[wv][3][lane] = okj ? __expf(v3 * we - gm) : 0.f;
    }
    // wave-local fence: ds_writes complete before cross-lane reads
    asm volatile("s_waitcnt lgkmcnt(0)" ::: "memory");
    const float* salh = sal[wv][hd8];

    int j = 0;
    for (; j + 7 < nj; j += 8) {
      int sj0 = __shfl(se, j + half);
      int sj1 = __shfl(se, j + 2 + half);
      int sj2 = __shfl(se, j + 4 + half);
      int sj3 = __shfl(se, j + 6 + half);
      uint4 q0 = *(const uint4*)(hb + (size_t)sj0 * HF + li * 8);
      uint4 q1 = *(const uint4*)(hb + (size_t)sj1 * HF + li * 8);
      uint4 q2 = *(const uint4*)(hb + (size_t)sj2 * HF + li * 8);
      uint4 q3 = *(const uint4*)(hb + (size_t)sj3 * HF + li * 8);
      float a0 = salh[j + half];
      float a1 = salh[j + 2 + half];
      float a2 = salh[j + 4 + half];
      float a3 = salh[j + 6 + half];
      den += (a0 + a1) + (a2 + a3);
      ax += a0 * bflo(q0.x) + a1 * bflo(q1.x) + a2 * bflo(q2.x) + a3 * bflo(q3.x);
      ay += a0 * bfhi(q0.x) + a1 * bfhi(q1.x) + a2 * bfhi(q2.x) + a3 * bfhi(q3.x);
      az += a0 * bflo(q0.y) + a1 * bflo(q1.y) + a2 * bflo(q2.y) + a3 * bflo(q3.y);
      aw += a0 * bfhi(q0.y) + a1 * bfhi(q1.y) + a2 * bfhi(q2.y) + a3 * bfhi(q3.y);
      bx += a0 * bflo(q0.z) + a1 * bflo(q1.z) + a2 * bflo(q2.z) + a3 * bflo(q3.z);
      by += a0 * bfhi(q0.z) + a1 * bfhi(q1.z) + a2 * bfhi(q2.z) + a3 * bfhi(q3.z);
      bz += a0 * bflo(q0.w) + a1 * bflo(q1.w) + a2 * bflo(q2.w) + a3 * bflo(q3.w);
      bw += a0 * bfhi(q0.w) + a1 * bfhi(q1.w) + a2 * bfhi(q2.w) + a3 * bfhi(q3.w);
    }
    for (; j < nj; j += 2) {
      int sj0 = __shfl(se, min(j + half, nj - 1));
      float a0 = (j + half < nj) ? salh[j + half] : 0.f;
      uint4 q0 = *(const uint4*)(hb + (size_t)sj0 * HF + li * 8);
      den += a0;
      ax += a0 * bflo(q0.x);
      ay += a0 * bfhi(q0.x);
      az += a0 * bflo(q0.y);
      aw += a0 * bfhi(q0.y);
      bx += a0 * bflo(q0.z);
      by += a0 * bfhi(q0.z);
      bz += a0 * bflo(q0.w);
      bw += a0 * bfhi(q0.w);
    }
  }

  // combine the two edge-halves (lane l <-> l^32 hold same columns)
  ax += __shfl_xor(ax, 32); ay += __shfl_xor(ay, 32);
  az += __shfl_xor(az, 32); aw += __shfl_xor(aw, 32);
  bx += __shfl_xor(bx, 32); by += __shfl_xor(by, 32);
  bz += __shfl_xor(bz, 32); bw += __shfl_xor(bw, 32);
  den += __shfl_xor(den, 32);
  float inv = 1.f / (den + 1e-10f);
  float4 r;
  if (half == 0) r = make_float4(ax * inv, ay * inv, az * inv, aw * inv);
  else           r = make_float4(bx * inv, by * inv, bz * inv, bw * inv);
  *(float4*)(out + (size_t)d * HF + li * 8 + half * 4) = r;
}

extern "C" void kernel_launch(void* const* d_in, const int* in_sizes, int n_in,
                              void* d_out, int out_size, void* d_ws, size_t ws_size,
                              hipStream_t stream) {
  const float* x     = (const float*)d_in[0];
  const int*   ei    = (const int*)d_in[1];
  const float* ew    = (const float*)d_in[2];
  const float* W     = (const float*)d_in[3];
  const float* a_src = (const float*)d_in[4];
  const float* a_dst = (const float*)d_in[5];
  float* out = (float*)d_out;

  // workspace: hb | xb | wb | as | ad | wa_src | wa_dst | [deg alloc gmax] |
  //            row_start | cursor | rec
  unsigned short* hb = (unsigned short*)d_ws;            // 25.6 MB
  unsigned short* xb = hb + (size_t)N_NODES * HF;        // 25.6 MB
  unsigned short* wbp = xb + (size_t)N_NODES * IN_F;     // 131 KB
  float* as = (float*)(wbp + 65536);                     // [node][4]
  float* ad = as + (size_t)HEADS * N_NODES;              // [node][4]
  float* wa_src = ad + (size_t)HEADS * N_NODES;          // 1024
  float* wa_dst = wa_src + HEADS * IN_F;                 // 1024
  int* deg       = (int*)(wa_dst + HEADS * IN_F);        // 50000
  int* alloc     = deg + N_NODES;                        // 1
  unsigned* gmax = (unsigned*)(alloc + 1);               // 1
  int* row_start = (int*)(gmax + 1);                     // 50000
  int* cursor    = row_start + N_NODES;                  // 50000
  int2* rec      = (int2*)(cursor + N_NODES);            // 6.4 MB

  const int* srcp = ei;
  const int* dstp = ei + N_EDGES;

  k_init<<<200, 256, 0, stream>>>(W, a_src, a_dst, deg, alloc, gmax, wa_src, wa_dst);
  k_prep<<<6250, 256, 0, stream>>>(x, W, dstp, wa_src, wa_dst, xb, wbp, deg, as, ad);
  k_alloc_scan<<<196, 256, 0, stream>>>(deg, alloc, row_start, cursor);
  k_gemm_scatter<<<2345, 256, 0, stream>>>(xb, wbp, hb, srcp, dstp, ew, as, ad,
                                           cursor, rec, gmax);
  k_agg<<<N_NODES / 4, 256, 0, stream>>>(row_start, deg, rec, as, ad, gmax, hb, out);
}